// Round 10
// baseline (57.279 us; speedup 1.0000x reference)
//
#include <hip/hip_runtime.h>
#include <cstdint>

// QuantumLatentLayer via MFMA: out[b,q] = cos(a)cos(th_q) - sin(a)cos(phi_q)sin(th_q),
// a = latent(32768x2048) . W^T(24x2048) + b.
// R7 (52.9us): MFMA removes W-delivery; 16 rows x 32 k per wave, zero LDS,
// compiler-managed counted vmcnt. R8 (+TLP) and R9 (+ILP) both ~neutral ->
// latency hiding is NOT the residual; achieved read BW (~5.6 TB/s) is.
// v10: grouped issue — 4 k-tiles' A-loads issued back-to-back so each row
// gets a 512B page-sequential burst (4 consecutive 128B lines) at the memory
// controller, instead of one isolated line per compute phase. Two groups in
// flight (static unrolled indexing, rule #20). VGPR ~175 < 256 @ 2 waves/SIMD.

#define NQ 24
#define LDIM 2048
#define BATCH 32768
#define NKT 64            // 2048 / 32 k-tiles

typedef __attribute__((ext_vector_type(8))) short bf16x8;
typedef __attribute__((ext_vector_type(4))) float f32x4;

union U4 { uint4 u; bf16x8 s; };

__device__ __forceinline__ uint cvt_pk_bf16(float lo, float hi) {
    uint r;
    asm("v_cvt_pk_bf16_f32 %0, %1, %2" : "=v"(r) : "v"(lo), "v"(hi));
    return r;
}

struct Grp { float4 a0[4]; float4 a1[4]; uint4 b0[4]; uint4 b1[4]; };

// Issue one group = 4 k-tiles. All 8 A-loads first (per row: 4 consecutive
// 128B lines = 512B burst), then the 8 L2-resident B fragment loads.
__device__ __forceinline__ void issueG(Grp& g, const float* ap, const uint4* bp, int t0) {
    #pragma unroll
    for (int i = 0; i < 4; i++) {
        g.a0[i] = *(const float4*)(ap + (t0 + i) * 32);
        g.a1[i] = *(const float4*)(ap + (t0 + i) * 32 + 4);
    }
    #pragma unroll
    for (int i = 0; i < 4; i++) {
        g.b0[i] = bp[(t0 + i) * 128];
        g.b1[i] = bp[(t0 + i) * 128 + 64];
    }
}

__device__ __forceinline__ void computeT(const float4 a0, const float4 a1,
                                         const uint4 b0u, const uint4 b1u,
                                         f32x4& c0, f32x4& c1) {
    // hi/lo bf16 split of the 8 fp32 A elements (RNE via v_cvt_pk_bf16_f32)
    uint h0 = cvt_pk_bf16(a0.x, a0.y);
    uint h1 = cvt_pk_bf16(a0.z, a0.w);
    uint h2 = cvt_pk_bf16(a1.x, a1.y);
    uint h3 = cvt_pk_bf16(a1.z, a1.w);
    float r0 = __uint_as_float(h0 << 16), r1 = __uint_as_float(h0 & 0xFFFF0000u);
    float r2 = __uint_as_float(h1 << 16), r3 = __uint_as_float(h1 & 0xFFFF0000u);
    float r4 = __uint_as_float(h2 << 16), r5 = __uint_as_float(h2 & 0xFFFF0000u);
    float r6 = __uint_as_float(h3 << 16), r7 = __uint_as_float(h3 & 0xFFFF0000u);
    uint l0 = cvt_pk_bf16(a0.x - r0, a0.y - r1);
    uint l1 = cvt_pk_bf16(a0.z - r2, a0.w - r3);
    uint l2 = cvt_pk_bf16(a1.x - r4, a1.y - r5);
    uint l3 = cvt_pk_bf16(a1.z - r6, a1.w - r7);
    U4 ah, al, b0, b1;
    ah.u = make_uint4(h0, h1, h2, h3);
    al.u = make_uint4(l0, l1, l2, l3);
    b0.u = b0u;
    b1.u = b1u;
    c0 = __builtin_amdgcn_mfma_f32_16x16x32_bf16(ah.s, b0.s, c0, 0, 0, 0);
    c1 = __builtin_amdgcn_mfma_f32_16x16x32_bf16(ah.s, b1.s, c1, 0, 0, 0);
    c0 = __builtin_amdgcn_mfma_f32_16x16x32_bf16(al.s, b0.s, c0, 0, 0, 0);
    c1 = __builtin_amdgcn_mfma_f32_16x16x32_bf16(al.s, b1.s, c1, 0, 0, 0);
}

__device__ __forceinline__ void computeG(const Grp& g, f32x4& c0, f32x4& c1) {
    #pragma unroll
    for (int i = 0; i < 4; i++)
        computeT(g.a0[i], g.a1[i], g.b0[i], g.b1[i], c0, c1);
}

__global__ __launch_bounds__(256, 2) void qll_main(
    const float* __restrict__ latent,
    const uint4* __restrict__ wb,     // prepacked W fragments, bf16, 128 KB
    const float* __restrict__ bvec,
    const float* __restrict__ ctv,    // cos(theta)
    const float* __restrict__ csv,    // cos(phi)*sin(theta)
    float* __restrict__ out)
{
    const int tid  = threadIdx.x;
    const int wave = tid >> 6;
    const int lane = tid & 63;
    const int mrow = lane & 15;
    const int kgrp = lane >> 4;
    const int row0 = (blockIdx.x * 4 + wave) * 16;

    const float* ap = latent + (size_t)(row0 + mrow) * LDIM + kgrp * 8;
    const uint4* bp = wb + lane;

    f32x4 c0 = {0.f, 0.f, 0.f, 0.f};
    f32x4 c1 = {0.f, 0.f, 0.f, 0.f};

    // Two groups (8 tiles) in flight; load-to-use distance = 8 tiles.
    Grp GA, GB;
    issueG(GA, ap, bp, 0);
    issueG(GB, ap, bp, 4);

    #pragma unroll 1
    for (int t = 0; t <= NKT - 16; t += 8) {   // t=0..48: compute 0..55, issue 8..63
        computeG(GA, c0, c1); issueG(GA, ap, bp, t + 8);
        computeG(GB, c0, c1); issueG(GB, ap, bp, t + 12);
    }
    computeG(GA, c0, c1);   // tiles 56..59
    computeG(GB, c0, c1);   // tiles 60..63

    // Epilogue: C/D layout (m89): col q = (lane&15) + 16*qt, row = kgrp*4 + r.
    #pragma unroll
    for (int qt = 0; qt < 2; qt++) {
        const int q = qt * 16 + mrow;
        const bool valid = (q < NQ);
        const float bv = valid ? bvec[q] : 0.f;
        const float ct = valid ? ctv[q]  : 0.f;
        const float cs = valid ? csv[q]  : 0.f;
        const f32x4 c = qt ? c1 : c0;
        #pragma unroll
        for (int r = 0; r < 4; r++) {
            const int row = row0 + kgrp * 4 + r;
            const float a = c[r] + bv;
            float s, co;
            __sincosf(a, &s, &co);
            if (valid) out[(size_t)row * NQ + q] = co * ct - s * cs;
        }
    }
}

// Prep: pack W into per-fragment bf16 layout. Fragment (kt, qt): 64 lanes x 16 B;
// lane l supplies q = qt*16 + (l&15), k = kt*32 + (l>>4)*8 + e (e=0..7), zero-pad
// q>=24. Flat ushort index = ((kt*2 + qt)*64 + l)*8 + e. Also ctcs[0..23]=cos(th),
// ctcs[24..47]=cos(phi)*sin(th).
__global__ __launch_bounds__(256) void qll_prep(
    const float* __restrict__ W, const float* __restrict__ params,
    ushort* __restrict__ wb, float* __restrict__ ctcs)
{
    const int idx = blockIdx.x * 256 + threadIdx.x;   // 0..65535
    const int kt  = idx >> 10;
    const int rem = idx & 1023;
    const int qt  = rem >> 9;
    const int l   = (rem >> 3) & 63;
    const int e   = rem & 7;
    const int q   = qt * 16 + (l & 15);
    const int k   = kt * 32 + (l >> 4) * 8 + e;
    float v = (q < NQ) ? W[q * LDIM + k] : 0.f;
    uint u = __float_as_uint(v);
    wb[idx] = (ushort)((u + 0x7FFF + ((u >> 16) & 1)) >> 16);   // RNE bf16
    if (idx < NQ) {
        float phi = params[3 * idx + 0];
        float th  = params[3 * idx + 1];
        ctcs[idx]      = cosf(th);
        ctcs[NQ + idx] = cosf(phi) * sinf(th);
    }
}

extern "C" void kernel_launch(void* const* d_in, const int* in_sizes, int n_in,
                              void* d_out, int out_size, void* d_ws, size_t ws_size,
                              hipStream_t stream) {
    (void)in_sizes; (void)n_in; (void)out_size; (void)ws_size;
    const float* latent = (const float*)d_in[0];
    const float* W      = (const float*)d_in[1];
    const float* bvec   = (const float*)d_in[2];
    const float* params = (const float*)d_in[3];
    float* out  = (float*)d_out;
    ushort* wb  = (ushort*)d_ws;                     // 65536 bf16 = 128 KB
    float* ctcs = (float*)d_ws + 32768;              // 48 floats

    hipLaunchKernelGGL(qll_prep, dim3(256), dim3(256), 0, stream,
                       W, params, wb, ctcs);
    hipLaunchKernelGGL(qll_main, dim3(BATCH / 64), dim3(256), 0, stream,
                       latent, (const uint4*)wb, bvec, ctcs, ctcs + NQ, out);
}

// Round 11
// 50.726 us; speedup vs baseline: 1.1292x; 1.1292x over previous
//
#include <hip/hip_runtime.h>
#include <cstdint>

// QuantumLatentLayer via MFMA: out[b,q] = cos(a)cos(th_q) - sin(a)cos(phi_q)sin(th_q),
// a = latent(32768x2048) . W^T(24x2048) + b.
// R7 (52.9us) = MFMA, direct-to-reg A (16 scattered 128B lines/inst). R8 (TLP),
// R9 (ILP), R10 (burst grouping) all neutral -> latency is hidden; achieved
// read BW (~5.65 TB/s) is the residual. v11 tests the LAST mechanism: request
// shape. A-panels staged to LDS with 512B-sequential-per-row global_load_lds
// (fill-shaped stream), MFMA fragments via XOR-swizzled ds_read_b128
// (pre-swizzled source, m173; 2 lanes/bank = free). R1/R2-proven counted
// vmcnt(16) ordering ("memory" clobber pins B-loads above, ds_reads below).

#define NQ 24
#define LDIM 2048
#define BATCH 32768
#define NPANEL 16         // panels of 128 k (= 4 MFMA k-tiles) per wave

typedef __attribute__((ext_vector_type(8))) short bf16x8;
typedef __attribute__((ext_vector_type(4))) float f32x4;

union U4 { uint4 u; bf16x8 s; };

typedef const __attribute__((address_space(1))) void* gas_t;
typedef __attribute__((address_space(3))) void* las_t;

__device__ __forceinline__ void gload_lds16(const float* g, float* l) {
    __builtin_amdgcn_global_load_lds((gas_t)g, (las_t)l, 16, 0, 0);
}

#define CVMCNT(n) asm volatile("s_waitcnt vmcnt(" #n ")" ::: "memory")

__device__ __forceinline__ uint cvt_pk_bf16(float lo, float hi) {
    uint r;
    asm("v_cvt_pk_bf16_f32 %0, %1, %2" : "=v"(r) : "v"(lo), "v"(hi));
    return r;
}

struct BGrp { uint4 b0[4]; uint4 b1[4]; };   // B fragments for one panel (4 tiles)

__device__ __forceinline__ void loadB(BGrp& g, const uint4* bp, int p) {
    #pragma unroll
    for (int t = 0; t < 4; t++) {
        g.b0[t] = bp[(p * 4 + t) * 128];
        g.b1[t] = bp[(p * 4 + t) * 128 + 64];
    }
}

// Stage panel p = [16 rows][128 floats] into ldst (linear 8KB). 8 insts; inst i
// covers rows 2i,2i+1: per row 512B SEQUENTIAL (4 consecutive 128B lines),
// 16B-slot-permuted by the involution s ^= (r&7) so the swizzled read below
// finds logical slot s of row r at phys slot s^(r&7). (m173 pattern.)
__device__ __forceinline__ void stagePanel(const float* lsrc, float* ldst,
                                           int p, int lane) {
    const int half = lane >> 5;       // row parity within instruction
    const int l32  = lane & 31;       // phys slot within row
    #pragma unroll
    for (int i = 0; i < 8; i++) {
        const int r = 2 * i + half;
        const int s = l32 ^ (r & 7);  // logical slot to fetch
        gload_lds16(lsrc + (size_t)r * LDIM + p * 128 + s * 4, ldst + i * 256);
    }
}

__device__ __forceinline__ void computeT(const float4 a0, const float4 a1,
                                         const uint4 b0u, const uint4 b1u,
                                         f32x4& c0, f32x4& c1) {
    // hi/lo bf16 split of the 8 fp32 A elements (RNE via v_cvt_pk_bf16_f32)
    uint h0 = cvt_pk_bf16(a0.x, a0.y);
    uint h1 = cvt_pk_bf16(a0.z, a0.w);
    uint h2 = cvt_pk_bf16(a1.x, a1.y);
    uint h3 = cvt_pk_bf16(a1.z, a1.w);
    float r0 = __uint_as_float(h0 << 16), r1 = __uint_as_float(h0 & 0xFFFF0000u);
    float r2 = __uint_as_float(h1 << 16), r3 = __uint_as_float(h1 & 0xFFFF0000u);
    float r4 = __uint_as_float(h2 << 16), r5 = __uint_as_float(h2 & 0xFFFF0000u);
    float r6 = __uint_as_float(h3 << 16), r7 = __uint_as_float(h3 & 0xFFFF0000u);
    uint l0 = cvt_pk_bf16(a0.x - r0, a0.y - r1);
    uint l1 = cvt_pk_bf16(a0.z - r2, a0.w - r3);
    uint l2 = cvt_pk_bf16(a1.x - r4, a1.y - r5);
    uint l3 = cvt_pk_bf16(a1.z - r6, a1.w - r7);
    U4 ah, al, b0, b1;
    ah.u = make_uint4(h0, h1, h2, h3);
    al.u = make_uint4(l0, l1, l2, l3);
    b0.u = b0u;
    b1.u = b1u;
    c0 = __builtin_amdgcn_mfma_f32_16x16x32_bf16(ah.s, b0.s, c0, 0, 0, 0);
    c1 = __builtin_amdgcn_mfma_f32_16x16x32_bf16(ah.s, b1.s, c1, 0, 0, 0);
    c0 = __builtin_amdgcn_mfma_f32_16x16x32_bf16(al.s, b0.s, c0, 0, 0, 0);
    c1 = __builtin_amdgcn_mfma_f32_16x16x32_bf16(al.s, b1.s, c1, 0, 0, 0);
}

// Compute one panel (4 k-tiles) from LDS. Lane reads row mrow, slots
// (t*8 + kgrp*2 (+1)) ^ (mrow&7): 16 lanes per kgrp spread over 8 XOR slots
// -> 2 lanes/bank-group = conflict-free (m136).
__device__ __forceinline__ void computePanel(const float* __restrict__ lbuf,
                                             const BGrp& g, int mrow, int kgrp,
                                             f32x4& c0, f32x4& c1) {
    const int base = mrow * 128;
    const int e0 = (((kgrp << 1) ^ (mrow & 7)) << 2);
    const int e1 = ((((kgrp << 1) | 1) ^ (mrow & 7)) << 2);
    #pragma unroll
    for (int t = 0; t < 4; t++) {
        float4 a0 = *(const float4*)(lbuf + base + t * 32 + e0);
        float4 a1 = *(const float4*)(lbuf + base + t * 32 + e1);
        computeT(a0, a1, g.b0[t], g.b1[t], c0, c1);
    }
}

__global__ __launch_bounds__(256, 2) void qll_main(
    const float* __restrict__ latent,
    const uint4* __restrict__ wb,     // prepacked W fragments, bf16, 128 KB
    const float* __restrict__ bvec,
    const float* __restrict__ ctv,    // cos(theta)
    const float* __restrict__ csv,    // cos(phi)*sin(theta)
    float* __restrict__ out)
{
    __shared__ __align__(16) float lds[4][2][2048];   // 64 KB -> 2 blocks/CU

    const int tid  = threadIdx.x;
    const int wave = tid >> 6;
    const int lane = tid & 63;
    const int mrow = lane & 15;
    const int kgrp = lane >> 4;
    const int row0 = (blockIdx.x * 4 + wave) * 16;

    const float* lsrc = latent + (size_t)row0 * LDIM;
    const uint4* bp   = wb + lane;

    float* lbuf0 = &lds[wave][0][0];
    float* lbuf1 = &lds[wave][1][0];

    f32x4 c0 = {0.f, 0.f, 0.f, 0.f};
    f32x4 c1 = {0.f, 0.f, 0.f, 0.f};

    BGrp B0, B1;
    stagePanel(lsrc, lbuf0, 0, lane);   // 8 VMEM
    loadB(B0, bp, 0);                   // 8 VMEM

    #pragma unroll 1
    for (int i = 0; i < 7; i++) {       // panels 0..13
        const int p = 2 * i;
        stagePanel(lsrc, lbuf1, p + 1, lane);
        loadB(B1, bp, p + 1);
        CVMCNT(16);                     // newest 16 = stage(p+1)+B(p+1); stage(p),B(p) done
        computePanel(lbuf0, B0, mrow, kgrp, c0, c1);
        stagePanel(lsrc, lbuf0, p + 2, lane);
        loadB(B0, bp, p + 2);
        CVMCNT(16);
        computePanel(lbuf1, B1, mrow, kgrp, c0, c1);
    }
    stagePanel(lsrc, lbuf1, 15, lane);
    loadB(B1, bp, 15);
    CVMCNT(16);
    computePanel(lbuf0, B0, mrow, kgrp, c0, c1);   // panel 14
    CVMCNT(0);
    computePanel(lbuf1, B1, mrow, kgrp, c0, c1);   // panel 15

    // Epilogue: C/D layout (m89): col q = (lane&15) + 16*qt, row = kgrp*4 + r.
    #pragma unroll
    for (int qt = 0; qt < 2; qt++) {
        const int q = qt * 16 + mrow;
        const bool valid = (q < NQ);
        const float bv = valid ? bvec[q] : 0.f;
        const float ct = valid ? ctv[q]  : 0.f;
        const float cs = valid ? csv[q]  : 0.f;
        const f32x4 c = qt ? c1 : c0;
        #pragma unroll
        for (int r = 0; r < 4; r++) {
            const int row = row0 + kgrp * 4 + r;
            const float a = c[r] + bv;
            float s, co;
            __sincosf(a, &s, &co);
            if (valid) out[(size_t)row * NQ + q] = co * ct - s * cs;
        }
    }
}

// Prep: pack W into per-fragment bf16 layout. Fragment (kt, qt): 64 lanes x 16 B;
// lane l supplies q = qt*16 + (l&15), k = kt*32 + (l>>4)*8 + e (e=0..7), zero-pad
// q>=24. Flat ushort index = ((kt*2 + qt)*64 + l)*8 + e. Also ctcs[0..23]=cos(th),
// ctcs[24..47]=cos(phi)*sin(th).
__global__ __launch_bounds__(256) void qll_prep(
    const float* __restrict__ W, const float* __restrict__ params,
    ushort* __restrict__ wb, float* __restrict__ ctcs)
{
    const int idx = blockIdx.x * 256 + threadIdx.x;   // 0..65535
    const int kt  = idx >> 10;
    const int rem = idx & 1023;
    const int qt  = rem >> 9;
    const int l   = (rem >> 3) & 63;
    const int e   = rem & 7;
    const int q   = qt * 16 + (l & 15);
    const int k   = kt * 32 + (l >> 4) * 8 + e;
    float v = (q < NQ) ? W[q * LDIM + k] : 0.f;
    uint u = __float_as_uint(v);
    wb[idx] = (ushort)((u + 0x7FFF + ((u >> 16) & 1)) >> 16);   // RNE bf16
    if (idx < NQ) {
        float phi = params[3 * idx + 0];
        float th  = params[3 * idx + 1];
        ctcs[idx]      = cosf(th);
        ctcs[NQ + idx] = cosf(phi) * sinf(th);
    }
}

extern "C" void kernel_launch(void* const* d_in, const int* in_sizes, int n_in,
                              void* d_out, int out_size, void* d_ws, size_t ws_size,
                              hipStream_t stream) {
    (void)in_sizes; (void)n_in; (void)out_size; (void)ws_size;
    const float* latent = (const float*)d_in[0];
    const float* W      = (const float*)d_in[1];
    const float* bvec   = (const float*)d_in[2];
    const float* params = (const float*)d_in[3];
    float* out  = (float*)d_out;
    ushort* wb  = (ushort*)d_ws;                     // 65536 bf16 = 128 KB
    float* ctcs = (float*)d_ws + 32768;              // 48 floats

    hipLaunchKernelGGL(qll_prep, dim3(256), dim3(256), 0, stream,
                       W, params, wb, ctcs);
    hipLaunchKernelGGL(qll_main, dim3(BATCH / 64), dim3(256), 0, stream,
                       latent, (const uint4*)wb, bvec, ctcs, ctcs + NQ, out);
}